// Round 4
// baseline (567.296 us; speedup 1.0000x reference)
//
#include <hip/hip_runtime.h>

typedef unsigned short u16;
typedef __attribute__((ext_vector_type(8))) short bf16x8;
typedef __attribute__((ext_vector_type(4))) float f32x4;

__device__ __forceinline__ float bf2f(u16 u) {
  union { unsigned u; float f; } c; c.u = ((unsigned)u) << 16; return c.f;
}
__device__ __forceinline__ u16 f2bf(float f) {
  union { float f; unsigned u; } c; c.f = f;
  unsigned u = c.u;
  return (u16)((u + 0x7FFFu + ((u >> 16) & 1u)) >> 16);
}

#define BB 32      // batch
#define CC 256     // channels
#define NN 1024    // H*W

// ---------------- 0. dtype detect: flag=1 if x is bf16, 0 if fp32 -----------
__global__ __launch_bounds__(256) void detect_kernel(const u16* __restrict__ x,
                                                     int* __restrict__ flag)
{
  int tid = threadIdx.x;
  unsigned u = x[(size_t)tid * 32768];
  int e = (u >> 7) & 0xFF;
  int sane = (e >= 97 && e <= 157) ? 1 : 0;
  __shared__ int cnt[256];
  cnt[tid] = sane;
  __syncthreads();
  for (int off = 128; off > 0; off >>= 1) {
    if (tid < off) cnt[tid] += cnt[tid + off];
    __syncthreads();
  }
  if (tid == 0) flag[0] = (cnt[0] >= 192) ? 1 : 0;
}

// ---------------- 0b. convert weights/biases to canonical bf16 --------------
__global__ __launch_bounds__(256) void convert_w_kernel(
    const void* __restrict__ Wk, const void* __restrict__ bk,
    const void* __restrict__ Wp, const void* __restrict__ bp,
    u16* __restrict__ Wkb, u16* __restrict__ bkb,
    u16* __restrict__ Wpb, u16* __restrict__ bpb, const int* __restrict__ flag)
{
  int b = blockIdx.x, t = threadIdx.x;
  const void* src; u16* dst; int idx, n;
  if (b < 768)       { src = Wk; dst = Wkb; idx = b * 256 + t;        n = 196608; }
  else if (b < 771)  { src = bk; dst = bkb; idx = (b - 768) * 256 + t; n = 768;   }
  else if (b < 1027) { src = Wp; dst = Wpb; idx = (b - 771) * 256 + t; n = 65536; }
  else               { src = bp; dst = bpb; idx = t;                  n = 256;    }
  if (idx < n)
    dst[idx] = flag[0] ? ((const u16*)src)[idx] : f2bf(((const float*)src)[idx]);
}

// ---------------- 1. BatchNorm stats: per-channel mean/var -> scale/shift ----
__global__ __launch_bounds__(256) void bn_stats_kernel(
    const void* __restrict__ xv, const void* __restrict__ gamma,
    const void* __restrict__ beta, float* __restrict__ scl,
    float* __restrict__ sft, const int* __restrict__ flag)
{
  int c = blockIdx.x;
  int tid = threadIdx.x;
  int isbf = flag[0];
  float s = 0.f, q = 0.f;
  if (isbf) {
    const u16* x = (const u16*)xv;
    for (int g = tid; g < 4096; g += 256) {
      int b = g >> 7;
      int n = (g & 127) * 8;
      bf16x8 v = *reinterpret_cast<const bf16x8*>(x + (((size_t)(b * CC + c)) << 10) + n);
      #pragma unroll
      for (int j = 0; j < 8; ++j) { float f = bf2f((u16)v[j]); s += f; q += f * f; }
    }
  } else {
    const float* x = (const float*)xv;
    for (int g = tid; g < 8192; g += 256) {
      int b = g >> 8;
      int n = (g & 255) * 4;
      float4 v = *reinterpret_cast<const float4*>(x + (((size_t)(b * CC + c)) << 10) + n);
      s += v.x + v.y + v.z + v.w;
      q += v.x * v.x + v.y * v.y + v.z * v.z + v.w * v.w;
    }
  }
  __shared__ float rs[256], rq[256];
  rs[tid] = s; rq[tid] = q;
  __syncthreads();
  for (int off = 128; off > 0; off >>= 1) {
    if (tid < off) { rs[tid] += rs[tid + off]; rq[tid] += rq[tid + off]; }
    __syncthreads();
  }
  if (tid == 0) {
    float mean = rs[0] * (1.f / 32768.f);
    float var  = rq[0] * (1.f / 32768.f) - mean * mean;
    float rstd = rsqrtf(var + 1e-5f);
    float gm = isbf ? bf2f(((const u16*)gamma)[c]) : ((const float*)gamma)[c];
    float bt = isbf ? bf2f(((const u16*)beta)[c])  : ((const float*)beta)[c];
    float g = gm * rstd;
    scl[c] = g;
    sft[c] = bt - mean * g;
  }
}

// ---------------- 2. normalize + transpose [B,C,N] -> t[B,N,C] (bf16) -------
__global__ __launch_bounds__(256) void norm_transpose_kernel(
    const void* __restrict__ xv, const float* __restrict__ scl,
    const float* __restrict__ sft, u16* __restrict__ t, const int* __restrict__ flag)
{
  __shared__ float tile[64][65];
  int b = blockIdx.z, n0 = blockIdx.x * 64, c0 = blockIdx.y * 64;
  int tid = threadIdx.x;
  int hi = tid >> 4, lo4 = (tid & 15) * 4;
  int isbf = flag[0];
  #pragma unroll
  for (int r = 0; r < 4; ++r) {
    int cl = r * 16 + hi;
    int c = c0 + cl;
    size_t off = (((size_t)(b * CC + c)) << 10) + n0 + lo4;
    float f0, f1, f2, f3;
    if (isbf) {
      ushort4 v = *reinterpret_cast<const ushort4*>((const u16*)xv + off);
      f0 = bf2f(v.x); f1 = bf2f(v.y); f2 = bf2f(v.z); f3 = bf2f(v.w);
    } else {
      float4 v = *reinterpret_cast<const float4*>((const float*)xv + off);
      f0 = v.x; f1 = v.y; f2 = v.z; f3 = v.w;
    }
    float sc = scl[c], sh = sft[c];
    tile[cl][lo4 + 0] = f0 * sc + sh;
    tile[cl][lo4 + 1] = f1 * sc + sh;
    tile[cl][lo4 + 2] = f2 * sc + sh;
    tile[cl][lo4 + 3] = f3 * sc + sh;
  }
  __syncthreads();
  #pragma unroll
  for (int r = 0; r < 4; ++r) {
    int nl = r * 16 + hi;
    ushort4 o;
    o.x = f2bf(tile[lo4 + 0][nl]);
    o.y = f2bf(tile[lo4 + 1][nl]);
    o.z = f2bf(tile[lo4 + 2][nl]);
    o.w = f2bf(tile[lo4 + 3][nl]);
    *reinterpret_cast<ushort4*>(t + ((size_t)(b * NN + n0 + nl)) * CC + c0 + lo4) = o;
  }
}

// ---------------- 3. generic NT bf16 GEMM: C[m,n] = scale*sum_k A[m,k]B[n,k] + bias[n]
// tstore=1: write C transposed per-batch-of-1024-rows: vt[row>>10][col][row&1023]
__global__ __launch_bounds__(256) void gemm_nt_kernel(
    const u16* __restrict__ A, int lda, size_t sA,
    const u16* __restrict__ B, int ldb, size_t sB,
    u16* __restrict__ C, int ldc, size_t sC,
    int K, const u16* __restrict__ bias, float scale, int tstore)
{
  __shared__ u16 As[128 * 40];
  __shared__ u16 Bs[128 * 40];
  int tid = threadIdx.x;
  int m0 = blockIdx.x * 128, n0 = blockIdx.y * 128;
  const u16* Ab = A + (size_t)blockIdx.z * sA;
  const u16* Bb = B + (size_t)blockIdx.z * sB;
  u16* Cb = C + (size_t)blockIdx.z * sC;

  int lane = tid & 63, w = tid >> 6;
  int lq = lane & 15, quad = lane >> 4;
  int wm = (w >> 1) * 64, wn = (w & 1) * 64;

  f32x4 zero = {0.f, 0.f, 0.f, 0.f};
  f32x4 acc[4][4];
  #pragma unroll
  for (int i = 0; i < 4; ++i)
    #pragma unroll
    for (int j = 0; j < 4; ++j) acc[i][j] = zero;

  int e0 = tid * 8, e1 = e0 + 2048;
  int r0row = e0 >> 5, r0col = e0 & 31;
  int r1row = e1 >> 5, r1col = e1 & 31;

  for (int k0 = 0; k0 < K; k0 += 32) {
    bf16x8 a0 = *reinterpret_cast<const bf16x8*>(Ab + (size_t)(m0 + r0row) * lda + k0 + r0col);
    bf16x8 a1 = *reinterpret_cast<const bf16x8*>(Ab + (size_t)(m0 + r1row) * lda + k0 + r1col);
    bf16x8 b0 = *reinterpret_cast<const bf16x8*>(Bb + (size_t)(n0 + r0row) * ldb + k0 + r0col);
    bf16x8 b1 = *reinterpret_cast<const bf16x8*>(Bb + (size_t)(n0 + r1row) * ldb + k0 + r1col);
    __syncthreads();
    *reinterpret_cast<bf16x8*>(&As[r0row * 40 + r0col]) = a0;
    *reinterpret_cast<bf16x8*>(&As[r1row * 40 + r1col]) = a1;
    *reinterpret_cast<bf16x8*>(&Bs[r0row * 40 + r0col]) = b0;
    *reinterpret_cast<bf16x8*>(&Bs[r1row * 40 + r1col]) = b1;
    __syncthreads();
    bf16x8 af[4], bfr[4];
    #pragma unroll
    for (int i = 0; i < 4; ++i) {
      af[i]  = *reinterpret_cast<const bf16x8*>(&As[(wm + i * 16 + lq) * 40 + quad * 8]);
      bfr[i] = *reinterpret_cast<const bf16x8*>(&Bs[(wn + i * 16 + lq) * 40 + quad * 8]);
    }
    #pragma unroll
    for (int i = 0; i < 4; ++i)
      #pragma unroll
      for (int j = 0; j < 4; ++j)
        acc[i][j] = __builtin_amdgcn_mfma_f32_16x16x32_bf16(af[i], bfr[j], acc[i][j], 0, 0, 0);
  }

  #pragma unroll
  for (int j = 0; j < 4; ++j) {
    int col = n0 + wn + j * 16 + lq;
    float bv = bias ? bf2f(bias[col]) : 0.f;
    #pragma unroll
    for (int i = 0; i < 4; ++i) {
      int rbase = m0 + wm + i * 16 + quad * 4;
      #pragma unroll
      for (int r = 0; r < 4; ++r) {
        float v = acc[i][j][r] * scale + bv;
        int rr = rbase + r;
        if (tstore) {
          // vt[b][col][n] with b=rr>>10, n=rr&1023 (B*C*N layout, C=256, N=1024)
          Cb[(size_t)(rr >> 10) * 262144 + (size_t)col * 1024 + (rr & 1023)] = f2bf(v);
        } else {
          Cb[(size_t)rr * ldc + col] = f2bf(v);
        }
      }
    }
  }
}

// ---------------- 4. row softmax in-place on bf16 S rows of length 1024 -----
__global__ __launch_bounds__(256) void softmax_kernel(u16* __restrict__ S)
{
  size_t row = blockIdx.x;
  u16* p = S + row * 1024;
  int tid = threadIdx.x;
  ushort4 v = *reinterpret_cast<const ushort4*>(p + tid * 4);
  float f0 = bf2f(v.x), f1 = bf2f(v.y), f2 = bf2f(v.z), f3 = bf2f(v.w);
  __shared__ float red[256];
  red[tid] = fmaxf(fmaxf(f0, f1), fmaxf(f2, f3));
  __syncthreads();
  for (int off = 128; off > 0; off >>= 1) {
    if (tid < off) red[tid] = fmaxf(red[tid], red[tid + off]);
    __syncthreads();
  }
  float mx = red[0];
  __syncthreads();
  float e0 = __expf(f0 - mx), e1 = __expf(f1 - mx), e2 = __expf(f2 - mx), e3 = __expf(f3 - mx);
  red[tid] = e0 + e1 + e2 + e3;
  __syncthreads();
  for (int off = 128; off > 0; off >>= 1) {
    if (tid < off) red[tid] += red[tid + off];
    __syncthreads();
  }
  float inv = 1.f / red[0];
  ushort4 o;
  o.x = f2bf(e0 * inv); o.y = f2bf(e1 * inv); o.z = f2bf(e2 * inv); o.w = f2bf(e3 * inv);
  *reinterpret_cast<ushort4*>(p + tid * 4) = o;
}

// ---------------- 6. final: out[b,c,n] = proj[b,n,c] + x[b,c,n]  (FP32 out!) -
__global__ __launch_bounds__(256) void final_kernel(const u16* __restrict__ proj,
                                                    const void* __restrict__ xv,
                                                    float* __restrict__ out,
                                                    const int* __restrict__ flag)
{
  __shared__ float tile[64][65];
  int b = blockIdx.z, n0 = blockIdx.x * 64, c0 = blockIdx.y * 64;
  int tid = threadIdx.x;
  int hi = tid >> 4, lo4 = (tid & 15) * 4;
  int isbf = flag[0];
  #pragma unroll
  for (int r = 0; r < 4; ++r) {
    int nl = r * 16 + hi;
    ushort4 v = *reinterpret_cast<const ushort4*>(
        proj + ((size_t)(b * NN + n0 + nl)) * CC + c0 + lo4);
    tile[nl][lo4] = bf2f(v.x); tile[nl][lo4 + 1] = bf2f(v.y);
    tile[nl][lo4 + 2] = bf2f(v.z); tile[nl][lo4 + 3] = bf2f(v.w);
  }
  __syncthreads();
  #pragma unroll
  for (int r = 0; r < 4; ++r) {
    int cl = r * 16 + hi;
    size_t idx = (((size_t)(b * CC + c0 + cl)) << 10) + n0 + lo4;
    float x0, x1, x2, x3;
    if (isbf) {
      ushort4 xv4 = *reinterpret_cast<const ushort4*>((const u16*)xv + idx);
      x0 = bf2f(xv4.x); x1 = bf2f(xv4.y); x2 = bf2f(xv4.z); x3 = bf2f(xv4.w);
    } else {
      float4 xv4 = *reinterpret_cast<const float4*>((const float*)xv + idx);
      x0 = xv4.x; x1 = xv4.y; x2 = xv4.z; x3 = xv4.w;
    }
    float4 o;
    o.x = tile[lo4 + 0][cl] + x0;
    o.y = tile[lo4 + 1][cl] + x1;
    o.z = tile[lo4 + 2][cl] + x2;
    o.w = tile[lo4 + 3][cl] + x3;
    *reinterpret_cast<float4*>(out + idx) = o;
  }
}

extern "C" void kernel_launch(void* const* d_in, const int* in_sizes, int n_in,
                              void* d_out, int out_size, void* d_ws, size_t ws_size,
                              hipStream_t stream) {
  const void* x     = d_in[0];
  const void* gamma = d_in[1];
  const void* beta  = d_in[2];
  const void* Wkqv  = d_in[3];
  const void* bkqv  = d_in[4];
  const void* Wproj = d_in[5];
  const void* bproj = d_in[6];
  float* out = (float*)d_out;          // reference output dtype = fp32 (33.5 MB)

  // ---- workspace layout: TOTAL 56.5 MB ----
  char* ws = (char*)d_ws;
  int*   flag = (int*)ws;                       // 4 B
  float* scl  = (float*)(ws + 256);             // 256 f32
  float* sft  = (float*)(ws + 1280);            // 256 f32
  u16* Wkb = (u16*)(ws + 4096);                 // 196608 bf16
  u16* bkb = Wkb + 196608;                      // 768
  u16* Wpb = bkb + 768;                         // 65536
  u16* bpb = Wpb + 65536;                       // 256
  u16* qk  = (u16*)(ws + 532480);               // [32768,512] bf16 = 32 MB
  u16* vt  = qk + (size_t)32768 * 512;          // [32,256,1024] bf16 = 16 MB
  u16* Sc  = vt + (size_t)32 * 256 * 1024;      // [4,1024,1024] bf16 = 8 MB (chunk)
  // d_out (33.5 MB fp32) doubles as bf16 scratch: t then o_pv, both dead
  // before final_kernel's fp32 write.
  u16* t    = (u16*)d_out;                      // [32768,256] bf16 = 16 MB
  u16* o_pv = (u16*)d_out;                      // [32768,256] bf16 = 16 MB
  u16* proj = qk;                               // reuse qk (dead after attention)

  // 0. dtype detect + weight conversion
  detect_kernel<<<dim3(1), dim3(256), 0, stream>>>((const u16*)x, flag);
  convert_w_kernel<<<dim3(1028), dim3(256), 0, stream>>>(
      Wkqv, bkqv, Wproj, bproj, Wkb, bkb, Wpb, bpb, flag);
  // 1. BN stats
  bn_stats_kernel<<<dim3(256), dim3(256), 0, stream>>>(x, gamma, beta, scl, sft, flag);
  // 2. normalize + transpose -> t [B,N,C]
  norm_transpose_kernel<<<dim3(16, 4, 32), dim3(256), 0, stream>>>(x, scl, sft, t, flag);
  // 3a. qk = t @ Wkqv[0:512]^T + b[0:512] : [32768,256]x[512,256]^T
  gemm_nt_kernel<<<dim3(256, 4, 1), dim3(256), 0, stream>>>(
      t, 256, 0, Wkb, 256, 0, qk, 512, 0, 256, bkb, 1.0f, 0);
  // 3b. vt[b,c,n] = (t @ Wkqv[512:768]^T + b[512:768])^T : transposed store
  gemm_nt_kernel<<<dim3(256, 2, 1), dim3(256), 0, stream>>>(
      t, 256, 0, Wkb + 512 * 256, 256, 0, vt, 0, 0, 256, bkb + 512, 1.0f, 1);
  // 4-7. attention in 8 chunks of 4 batches (Sc reused)
  for (int ch = 0; ch < 8; ++ch) {
    const u16* qc = qk + (size_t)ch * 4 * 1024 * 512;
    // S = Q K^T / 16 : per batch [1024,256]x[1024,256]^T
    gemm_nt_kernel<<<dim3(8, 8, 4), dim3(256), 0, stream>>>(
        qc, 512, (size_t)1024 * 512, qc + 256, 512, (size_t)1024 * 512,
        Sc, 1024, (size_t)1024 * 1024, 256, nullptr, 0.0625f, 0);
    // softmax rows in-place
    softmax_kernel<<<dim3(4096), dim3(256), 0, stream>>>(Sc);
    // o_pv = P @ V : [1024,1024]x[256,1024]^T per batch
    gemm_nt_kernel<<<dim3(8, 2, 4), dim3(256), 0, stream>>>(
        Sc, 1024, (size_t)1024 * 1024, vt + (size_t)ch * 4 * 262144, 1024, (size_t)262144,
        o_pv + (size_t)ch * 4 * 262144, 256, (size_t)262144, 1024, nullptr, 1.0f, 0);
  }
  // 8. proj = o_pv @ Wproj^T + bproj : [32768,256]x[256,256]^T  (proj in qk region)
  gemm_nt_kernel<<<dim3(256, 2, 1), dim3(256), 0, stream>>>(
      o_pv, 256, 0, Wpb, 256, 0, proj, 256, 0, 256, bpb, 1.0f, 0);
  // 9. out = transpose(proj) + x  — fp32 store (o_pv dead)
  final_kernel<<<dim3(16, 4, 32), dim3(256), 0, stream>>>(proj, x, out, flag);
}

// Round 5
// 271.085 us; speedup vs baseline: 2.0927x; 2.0927x over previous
//
#include <hip/hip_runtime.h>

typedef unsigned short u16;
typedef __attribute__((ext_vector_type(8))) short bf16x8;
typedef __attribute__((ext_vector_type(4))) float f32x4;

__device__ __forceinline__ float bf2f(u16 u) {
  union { unsigned u; float f; } c; c.u = ((unsigned)u) << 16; return c.f;
}
__device__ __forceinline__ u16 f2bf(float f) {
  union { float f; unsigned u; } c; c.f = f;
  unsigned u = c.u;
  return (u16)((u + 0x7FFFu + ((u >> 16) & 1u)) >> 16);
}

#define BB 32      // batch
#define CC 256     // channels
#define NN 1024    // H*W

// ---------------- 0. convert weights/biases fp32 -> bf16 --------------------
__global__ __launch_bounds__(256) void convert_w_kernel(
    const float* __restrict__ Wk, const float* __restrict__ bk,
    const float* __restrict__ Wp, const float* __restrict__ bp,
    u16* __restrict__ Wkb, u16* __restrict__ bkb,
    u16* __restrict__ Wpb, u16* __restrict__ bpb)
{
  int b = blockIdx.x, t = threadIdx.x;
  const float* src; u16* dst; int idx, n;
  if (b < 768)       { src = Wk; dst = Wkb; idx = b * 256 + t;        n = 196608; }
  else if (b < 771)  { src = bk; dst = bkb; idx = (b - 768) * 256 + t; n = 768;   }
  else if (b < 1027) { src = Wp; dst = Wpb; idx = (b - 771) * 256 + t; n = 65536; }
  else               { src = bp; dst = bpb; idx = t;                  n = 256;    }
  if (idx < n) dst[idx] = f2bf(src[idx]);
}

// ---------------- 1. BatchNorm stats: per-channel mean/var -> scale/shift ----
__global__ __launch_bounds__(256) void bn_stats_kernel(
    const float* __restrict__ x, const float* __restrict__ gamma,
    const float* __restrict__ beta, float* __restrict__ scl, float* __restrict__ sft)
{
  int c = blockIdx.x;
  int tid = threadIdx.x;
  float s = 0.f, q = 0.f;
  for (int g = tid; g < 8192; g += 256) {
    int b = g >> 8;
    int n = (g & 255) * 4;
    float4 v = *reinterpret_cast<const float4*>(x + (((size_t)(b * CC + c)) << 10) + n);
    s += v.x + v.y + v.z + v.w;
    q += v.x * v.x + v.y * v.y + v.z * v.z + v.w * v.w;
  }
  __shared__ float rs[256], rq[256];
  rs[tid] = s; rq[tid] = q;
  __syncthreads();
  for (int off = 128; off > 0; off >>= 1) {
    if (tid < off) { rs[tid] += rs[tid + off]; rq[tid] += rq[tid + off]; }
    __syncthreads();
  }
  if (tid == 0) {
    float mean = rs[0] * (1.f / 32768.f);
    float var  = rq[0] * (1.f / 32768.f) - mean * mean;
    float rstd = rsqrtf(var + 1e-5f);
    float g = gamma[c] * rstd;
    scl[c] = g;
    sft[c] = beta[c] - mean * g;
  }
}

// ---------------- 2. normalize + transpose [B,C,N] -> t[B,N,C] (bf16) -------
__global__ __launch_bounds__(256) void norm_transpose_kernel(
    const float* __restrict__ x, const float* __restrict__ scl,
    const float* __restrict__ sft, u16* __restrict__ t)
{
  __shared__ float tile[64][65];
  int b = blockIdx.z, n0 = blockIdx.x * 64, c0 = blockIdx.y * 64;
  int tid = threadIdx.x;
  int hi = tid >> 4, lo4 = (tid & 15) * 4;
  #pragma unroll
  for (int r = 0; r < 4; ++r) {
    int cl = r * 16 + hi;
    int c = c0 + cl;
    float4 v = *reinterpret_cast<const float4*>(
        x + (((size_t)(b * CC + c)) << 10) + n0 + lo4);
    float sc = scl[c], sh = sft[c];
    tile[cl][lo4 + 0] = v.x * sc + sh;
    tile[cl][lo4 + 1] = v.y * sc + sh;
    tile[cl][lo4 + 2] = v.z * sc + sh;
    tile[cl][lo4 + 3] = v.w * sc + sh;
  }
  __syncthreads();
  #pragma unroll
  for (int r = 0; r < 4; ++r) {
    int nl = r * 16 + hi;
    ushort4 o;
    o.x = f2bf(tile[lo4 + 0][nl]);
    o.y = f2bf(tile[lo4 + 1][nl]);
    o.z = f2bf(tile[lo4 + 2][nl]);
    o.w = f2bf(tile[lo4 + 3][nl]);
    *reinterpret_cast<ushort4*>(t + ((size_t)(b * NN + n0 + nl)) * CC + c0 + lo4) = o;
  }
}

// ---------------- 3. NT bf16 GEMM: C[m,n] = scale*sum_k A[m,k]B[n,k] + bias[n]
// mode 0: plain bf16 store to Cb[rr*ldc+col]
// mode 1: transposed store vt[rr>>10][col][rr&1023] (bf16)
// mode 2: fused residual: outf[(b*256+col)*1024+n] = v + xres[...] (fp32 float4)
__global__ __launch_bounds__(256) void gemm_nt_kernel(
    const u16* __restrict__ A, int lda, size_t sA,
    const u16* __restrict__ B, int ldb, size_t sB,
    u16* __restrict__ C, int ldc, size_t sC,
    int K, const u16* __restrict__ bias, float scale, int mode,
    const float* __restrict__ xres, float* __restrict__ outf)
{
  __shared__ u16 As[128 * 40];
  __shared__ u16 Bs[128 * 40];
  int tid = threadIdx.x;
  int m0 = blockIdx.x * 128, n0 = blockIdx.y * 128;
  const u16* Ab = A + (size_t)blockIdx.z * sA;
  const u16* Bb = B + (size_t)blockIdx.z * sB;
  u16* Cb = C + (size_t)blockIdx.z * sC;

  int lane = tid & 63, w = tid >> 6;
  int lq = lane & 15, quad = lane >> 4;
  int wm = (w >> 1) * 64, wn = (w & 1) * 64;

  f32x4 zero = {0.f, 0.f, 0.f, 0.f};
  f32x4 acc[4][4];
  #pragma unroll
  for (int i = 0; i < 4; ++i)
    #pragma unroll
    for (int j = 0; j < 4; ++j) acc[i][j] = zero;

  int e0 = tid * 8, e1 = e0 + 2048;
  int r0row = e0 >> 5, r0col = e0 & 31;
  int r1row = e1 >> 5, r1col = e1 & 31;

  for (int k0 = 0; k0 < K; k0 += 32) {
    bf16x8 a0 = *reinterpret_cast<const bf16x8*>(Ab + (size_t)(m0 + r0row) * lda + k0 + r0col);
    bf16x8 a1 = *reinterpret_cast<const bf16x8*>(Ab + (size_t)(m0 + r1row) * lda + k0 + r1col);
    bf16x8 b0 = *reinterpret_cast<const bf16x8*>(Bb + (size_t)(n0 + r0row) * ldb + k0 + r0col);
    bf16x8 b1 = *reinterpret_cast<const bf16x8*>(Bb + (size_t)(n0 + r1row) * ldb + k0 + r1col);
    __syncthreads();
    *reinterpret_cast<bf16x8*>(&As[r0row * 40 + r0col]) = a0;
    *reinterpret_cast<bf16x8*>(&As[r1row * 40 + r1col]) = a1;
    *reinterpret_cast<bf16x8*>(&Bs[r0row * 40 + r0col]) = b0;
    *reinterpret_cast<bf16x8*>(&Bs[r1row * 40 + r1col]) = b1;
    __syncthreads();
    bf16x8 af[4], bfr[4];
    #pragma unroll
    for (int i = 0; i < 4; ++i) {
      af[i]  = *reinterpret_cast<const bf16x8*>(&As[(wm + i * 16 + lq) * 40 + quad * 8]);
      bfr[i] = *reinterpret_cast<const bf16x8*>(&Bs[(wn + i * 16 + lq) * 40 + quad * 8]);
    }
    #pragma unroll
    for (int i = 0; i < 4; ++i)
      #pragma unroll
      for (int j = 0; j < 4; ++j)
        acc[i][j] = __builtin_amdgcn_mfma_f32_16x16x32_bf16(af[i], bfr[j], acc[i][j], 0, 0, 0);
  }

  #pragma unroll
  for (int j = 0; j < 4; ++j) {
    int col = n0 + wn + j * 16 + lq;
    float bv = bias ? bf2f(bias[col]) : 0.f;
    #pragma unroll
    for (int i = 0; i < 4; ++i) {
      int rbase = m0 + wm + i * 16 + quad * 4;
      if (mode == 2) {
        // rows rbase..rbase+3 are 4 consecutive n within one batch
        int b = rbase >> 10, n = rbase & 1023;
        size_t idx = (((size_t)(b * CC + col)) << 10) + n;
        float4 xv = *reinterpret_cast<const float4*>(xres + idx);
        float4 o;
        o.x = acc[i][j][0] * scale + bv + xv.x;
        o.y = acc[i][j][1] * scale + bv + xv.y;
        o.z = acc[i][j][2] * scale + bv + xv.z;
        o.w = acc[i][j][3] * scale + bv + xv.w;
        *reinterpret_cast<float4*>(outf + idx) = o;
      } else if (mode == 1) {
        int b = rbase >> 10, n = rbase & 1023;
        ushort4 o;
        o.x = f2bf(acc[i][j][0] * scale + bv);
        o.y = f2bf(acc[i][j][1] * scale + bv);
        o.z = f2bf(acc[i][j][2] * scale + bv);
        o.w = f2bf(acc[i][j][3] * scale + bv);
        *reinterpret_cast<ushort4*>(&Cb[(size_t)b * 262144 + (size_t)col * 1024 + n]) = o;
      } else {
        #pragma unroll
        for (int r = 0; r < 4; ++r)
          Cb[(size_t)(rbase + r) * ldc + col] = f2bf(acc[i][j][r] * scale + bv);
      }
    }
  }
}

// ---------------- 4. wave-per-row softmax in-place, rows of 1024 bf16 -------
__global__ __launch_bounds__(256) void softmax_kernel(u16* __restrict__ S)
{
  int row = blockIdx.x * 4 + (threadIdx.x >> 6);
  int lane = threadIdx.x & 63;
  u16* p = S + (size_t)row * 1024 + lane * 16;
  bf16x8 v0 = *reinterpret_cast<const bf16x8*>(p);
  bf16x8 v1 = *reinterpret_cast<const bf16x8*>(p + 8);
  float f[16];
  #pragma unroll
  for (int j = 0; j < 8; ++j) { f[j] = bf2f((u16)v0[j]); f[8 + j] = bf2f((u16)v1[j]); }
  float mx = f[0];
  #pragma unroll
  for (int j = 1; j < 16; ++j) mx = fmaxf(mx, f[j]);
  #pragma unroll
  for (int off = 32; off > 0; off >>= 1) mx = fmaxf(mx, __shfl_xor(mx, off, 64));
  float s = 0.f;
  #pragma unroll
  for (int j = 0; j < 16; ++j) { f[j] = __expf(f[j] - mx); s += f[j]; }
  #pragma unroll
  for (int off = 32; off > 0; off >>= 1) s += __shfl_xor(s, off, 64);
  float inv = 1.f / s;
  #pragma unroll
  for (int j = 0; j < 8; ++j) { v0[j] = (short)f2bf(f[j] * inv); v1[j] = (short)f2bf(f[8 + j] * inv); }
  *reinterpret_cast<bf16x8*>(p) = v0;
  *reinterpret_cast<bf16x8*>(p + 8) = v1;
}

extern "C" void kernel_launch(void* const* d_in, const int* in_sizes, int n_in,
                              void* d_out, int out_size, void* d_ws, size_t ws_size,
                              hipStream_t stream) {
  const float* x     = (const float*)d_in[0];
  const float* gamma = (const float*)d_in[1];
  const float* beta  = (const float*)d_in[2];
  const float* Wkqv  = (const float*)d_in[3];
  const float* bkqv  = (const float*)d_in[4];
  const float* Wproj = (const float*)d_in[5];
  const float* bproj = (const float*)d_in[6];
  float* out = (float*)d_out;          // fp32 [32,256,32,32]

  // ---- workspace layout ----
  char* ws = (char*)d_ws;
  float* scl  = (float*)ws;                     // 256 f32
  float* sft  = (float*)(ws + 1024);            // 256 f32
  u16* Wkb = (u16*)(ws + 4096);                 // 196608 bf16
  u16* bkb = Wkb + 196608;
  u16* Wpb = bkb + 768;
  u16* bpb = Wpb + 65536;
  u16* qk   = (u16*)(ws + 532480);              // [32768,512] bf16 = 32 MB
  u16* vt   = qk + (size_t)32768 * 512;         // [32,256,1024] bf16 = 16 MB
  u16* o_pv = vt + (size_t)32 * 256 * 1024;     // [32768,256] bf16 = 16 MB
  u16* Sc   = o_pv + (size_t)32768 * 256;       // S chunk region (rest of ws)
  size_t s_base = 532480 + (33554432 + 16777216 + 16777216);
  // batches per S chunk (2 MB per batch), clamped [1,32]
  long avail = (long)ws_size - (long)s_base;
  int bpc = (int)(avail / 2097152);
  if (bpc < 1) bpc = 1;
  if (bpc > 32) bpc = 32;
  // t lives in d_out (bf16 scratch, dead before mode-2 fp32 writes)
  u16* t = (u16*)d_out;

  // 0. weight conversion
  convert_w_kernel<<<dim3(1028), dim3(256), 0, stream>>>(
      Wkqv, bkqv, Wproj, bproj, Wkb, bkb, Wpb, bpb);
  // 1. BN stats
  bn_stats_kernel<<<dim3(256), dim3(256), 0, stream>>>(x, gamma, beta, scl, sft);
  // 2. normalize + transpose -> t [B,N,C]
  norm_transpose_kernel<<<dim3(16, 4, 32), dim3(256), 0, stream>>>(x, scl, sft, t);
  // 3a. qk = t @ Wkqv[0:512]^T + b[0:512]
  gemm_nt_kernel<<<dim3(256, 4, 1), dim3(256), 0, stream>>>(
      t, 256, 0, Wkb, 256, 0, qk, 512, 0, 256, bkb, 1.0f, 0, nullptr, nullptr);
  // 3b. vt[b,c,n] = (t @ Wkqv[512:768]^T + b[512:768])^T
  gemm_nt_kernel<<<dim3(256, 2, 1), dim3(256), 0, stream>>>(
      t, 256, 0, Wkb + 512 * 256, 256, 0, vt, 0, 0, 256, bkb + 512, 1.0f, 1,
      nullptr, nullptr);
  // 4-7. attention, bpc batches per chunk
  for (int b0 = 0; b0 < 32; b0 += bpc) {
    int nb = (32 - b0 < bpc) ? (32 - b0) : bpc;
    const u16* qc = qk + (size_t)b0 * 1024 * 512;
    // S = Q K^T / 16
    gemm_nt_kernel<<<dim3(8, 8, nb), dim3(256), 0, stream>>>(
        qc, 512, (size_t)1024 * 512, qc + 256, 512, (size_t)1024 * 512,
        Sc, 1024, (size_t)1024 * 1024, 256, nullptr, 0.0625f, 0, nullptr, nullptr);
    // softmax (wave per row, 4 rows/block)
    softmax_kernel<<<dim3(nb * 256), dim3(256), 0, stream>>>(Sc);
    // o_pv = P @ V
    gemm_nt_kernel<<<dim3(8, 2, nb), dim3(256), 0, stream>>>(
        Sc, 1024, (size_t)1024 * 1024, vt + (size_t)b0 * 262144, 1024, (size_t)262144,
        o_pv + (size_t)b0 * 262144, 256, (size_t)262144, 1024, nullptr, 1.0f, 0,
        nullptr, nullptr);
  }
  // 8+9 fused: out[b,c,n] = (o_pv @ Wproj^T + bproj)[n,c] + x[b,c,n]  (fp32)
  gemm_nt_kernel<<<dim3(256, 2, 1), dim3(256), 0, stream>>>(
      o_pv, 256, 0, Wpb, 256, 0, nullptr, 0, 0, 256, bpb, 1.0f, 2, x, out);
}

// Round 6
// 251.263 us; speedup vs baseline: 2.2578x; 1.0789x over previous
//
#include <hip/hip_runtime.h>

typedef unsigned short u16;
typedef __attribute__((ext_vector_type(8))) short bf16x8;
typedef __attribute__((ext_vector_type(4))) float f32x4;

__device__ __forceinline__ float bf2f(u16 u) {
  union { unsigned u; float f; } c; c.u = ((unsigned)u) << 16; return c.f;
}
__device__ __forceinline__ u16 f2bf(float f) {
  union { float f; unsigned u; } c; c.f = f;
  unsigned u = c.u;
  return (u16)((u + 0x7FFFu + ((u >> 16) & 1u)) >> 16);
}
// async global->LDS, 16B per lane; LDS dest = wave-uniform base + lane*16
__device__ __forceinline__ void gld16(const void* g, void* l) {
  __builtin_amdgcn_global_load_lds(
      (__attribute__((address_space(1))) void*)g,
      (__attribute__((address_space(3))) void*)l, 16, 0, 0);
}

#define BB 32      // batch
#define CC 256     // channels
#define NN 1024    // H*W

// ---------------- 0. convert weights/biases fp32 -> bf16 --------------------
__global__ __launch_bounds__(256) void convert_w_kernel(
    const float* __restrict__ Wk, const float* __restrict__ bk,
    const float* __restrict__ Wp, const float* __restrict__ bp,
    u16* __restrict__ Wkb, u16* __restrict__ bkb,
    u16* __restrict__ Wpb, u16* __restrict__ bpb)
{
  int b = blockIdx.x, t = threadIdx.x;
  const float* src; u16* dst; int idx, n;
  if (b < 768)       { src = Wk; dst = Wkb; idx = b * 256 + t;        n = 196608; }
  else if (b < 771)  { src = bk; dst = bkb; idx = (b - 768) * 256 + t; n = 768;   }
  else if (b < 1027) { src = Wp; dst = Wpb; idx = (b - 771) * 256 + t; n = 65536; }
  else               { src = bp; dst = bpb; idx = t;                  n = 256;    }
  if (idx < n) dst[idx] = f2bf(src[idx]);
}

// ---------------- 1. BatchNorm stats: per-channel mean/var -> scale/shift ----
__global__ __launch_bounds__(256) void bn_stats_kernel(
    const float* __restrict__ x, const float* __restrict__ gamma,
    const float* __restrict__ beta, float* __restrict__ scl, float* __restrict__ sft)
{
  int c = blockIdx.x;
  int tid = threadIdx.x;
  float s = 0.f, q = 0.f;
  for (int g = tid; g < 8192; g += 256) {
    int b = g >> 8;
    int n = (g & 255) * 4;
    float4 v = *reinterpret_cast<const float4*>(x + (((size_t)(b * CC + c)) << 10) + n);
    s += v.x + v.y + v.z + v.w;
    q += v.x * v.x + v.y * v.y + v.z * v.z + v.w * v.w;
  }
  __shared__ float rs[256], rq[256];
  rs[tid] = s; rq[tid] = q;
  __syncthreads();
  for (int off = 128; off > 0; off >>= 1) {
    if (tid < off) { rs[tid] += rs[tid + off]; rq[tid] += rq[tid + off]; }
    __syncthreads();
  }
  if (tid == 0) {
    float mean = rs[0] * (1.f / 32768.f);
    float var  = rq[0] * (1.f / 32768.f) - mean * mean;
    float rstd = rsqrtf(var + 1e-5f);
    float g = gamma[c] * rstd;
    scl[c] = g;
    sft[c] = beta[c] - mean * g;
  }
}

// ---------------- 2. normalize + transpose [B,C,N] -> t[B,N,C] (bf16) -------
__global__ __launch_bounds__(256) void norm_transpose_kernel(
    const float* __restrict__ x, const float* __restrict__ scl,
    const float* __restrict__ sft, u16* __restrict__ t)
{
  __shared__ float tile[64][65];
  int b = blockIdx.z, n0 = blockIdx.x * 64, c0 = blockIdx.y * 64;
  int tid = threadIdx.x;
  int hi = tid >> 4, lo4 = (tid & 15) * 4;
  #pragma unroll
  for (int r = 0; r < 4; ++r) {
    int cl = r * 16 + hi;
    int c = c0 + cl;
    float4 v = *reinterpret_cast<const float4*>(
        x + (((size_t)(b * CC + c)) << 10) + n0 + lo4);
    float sc = scl[c], sh = sft[c];
    tile[cl][lo4 + 0] = v.x * sc + sh;
    tile[cl][lo4 + 1] = v.y * sc + sh;
    tile[cl][lo4 + 2] = v.z * sc + sh;
    tile[cl][lo4 + 3] = v.w * sc + sh;
  }
  __syncthreads();
  #pragma unroll
  for (int r = 0; r < 4; ++r) {
    int nl = r * 16 + hi;
    ushort4 o;
    o.x = f2bf(tile[lo4 + 0][nl]);
    o.y = f2bf(tile[lo4 + 1][nl]);
    o.z = f2bf(tile[lo4 + 2][nl]);
    o.w = f2bf(tile[lo4 + 3][nl]);
    *reinterpret_cast<ushort4*>(t + ((size_t)(b * NN + n0 + nl)) * CC + c0 + lo4) = o;
  }
}

// ---------------- 3. NT bf16 GEMM, m97 structure (global_load_lds staging) ---
// C[m,n] = f(scale * sum_k A[m,k]*B[n,k] + bias[n])
// mode 0: plain bf16 store
// mode 1: transposed store vt[rr>>10][col][rr&1023] (bf16, ushort4)
// mode 2: proj + residual: outf[(b*256+col)<<10 | n] = v + xres[...] (fp32)
// mode 3: S-exp: store exp(scale*acc) bf16, atomicAdd row sums into rowsum
// mode 4: PV: store acc * (1/rowsum[row]) bf16
__global__ __launch_bounds__(256) void gemm_nt_kernel(
    const u16* __restrict__ A, int lda, size_t sA,
    const u16* __restrict__ B, int ldb, size_t sB,
    u16* __restrict__ C, int ldc, size_t sC,
    int K, const u16* __restrict__ bias, float scale, int mode,
    const float* __restrict__ xres, float* __restrict__ outf,
    float* __restrict__ rowsum)
{
  __shared__ u16 As[128 * 32];   // unpadded: global_load_lds needs lane-contiguous
  __shared__ u16 Bs[128 * 32];
  int tid = threadIdx.x;
  int m0 = blockIdx.x * 128, n0 = blockIdx.y * 128;
  const u16* Ab = A + (size_t)blockIdx.z * sA;
  const u16* Bb = B + (size_t)blockIdx.z * sB;
  u16* Cb = C + (size_t)blockIdx.z * sC;

  int lane = tid & 63, w = tid >> 6;
  int lq = lane & 15, quad = lane >> 4;
  int wm = (w >> 1) * 64, wn = (w & 1) * 64;
  int ar = lane >> 2, ac = (lane & 3) * 8;   // staging: 4 lanes/row, 16B each
  int rb = w * 32;                            // wave's 32-row staging slice

  f32x4 zero = {0.f, 0.f, 0.f, 0.f};
  f32x4 acc[4][4];
  #pragma unroll
  for (int i = 0; i < 4; ++i)
    #pragma unroll
    for (int j = 0; j < 4; ++j) acc[i][j] = zero;

  for (int k0 = 0; k0 < K; k0 += 32) {
    __syncthreads();   // previous tile's ds_reads complete before overwrite
    gld16(Ab + (size_t)(m0 + rb +      ar) * lda + k0 + ac, &As[(rb     ) * 32]);
    gld16(Ab + (size_t)(m0 + rb + 16 + ar) * lda + k0 + ac, &As[(rb + 16) * 32]);
    gld16(Bb + (size_t)(n0 + rb +      ar) * ldb + k0 + ac, &Bs[(rb     ) * 32]);
    gld16(Bb + (size_t)(n0 + rb + 16 + ar) * ldb + k0 + ac, &Bs[(rb + 16) * 32]);
    __syncthreads();   // compiler drains vmcnt before barrier
    bf16x8 af[4], bfr[4];
    #pragma unroll
    for (int i = 0; i < 4; ++i) {
      af[i]  = *reinterpret_cast<const bf16x8*>(&As[(wm + i * 16 + lq) * 32 + quad * 8]);
      bfr[i] = *reinterpret_cast<const bf16x8*>(&Bs[(wn + i * 16 + lq) * 32 + quad * 8]);
    }
    #pragma unroll
    for (int i = 0; i < 4; ++i)
      #pragma unroll
      for (int j = 0; j < 4; ++j)
        acc[i][j] = __builtin_amdgcn_mfma_f32_16x16x32_bf16(af[i], bfr[j], acc[i][j], 0, 0, 0);
  }

  if (mode == 3) {
    // store p = exp(scale*acc) and accumulate row sums
    #pragma unroll
    for (int i = 0; i < 4; ++i) {
      int rbase = m0 + wm + i * 16 + quad * 4;
      #pragma unroll
      for (int r = 0; r < 4; ++r) {
        int row = rbase + r;
        float part = 0.f;
        #pragma unroll
        for (int j = 0; j < 4; ++j) {
          int col = n0 + wn + j * 16 + lq;
          float p = __expf(acc[i][j][r] * scale);
          u16 pb = f2bf(p);
          Cb[(size_t)row * ldc + col] = pb;
          part += bf2f(pb);
        }
        part += __shfl_xor(part, 1, 64);
        part += __shfl_xor(part, 2, 64);
        part += __shfl_xor(part, 4, 64);
        part += __shfl_xor(part, 8, 64);
        if (lq == 0) atomicAdd(&rowsum[blockIdx.z * 1024 + row], part);
      }
    }
  } else if (mode == 4) {
    #pragma unroll
    for (int i = 0; i < 4; ++i) {
      int rbase = m0 + wm + i * 16 + quad * 4;
      #pragma unroll
      for (int r = 0; r < 4; ++r) {
        int row = rbase + r;
        float linv = 1.f / rowsum[blockIdx.z * 1024 + row];
        #pragma unroll
        for (int j = 0; j < 4; ++j) {
          int col = n0 + wn + j * 16 + lq;
          Cb[(size_t)row * ldc + col] = f2bf(acc[i][j][r] * linv);
        }
      }
    }
  } else {
    #pragma unroll
    for (int j = 0; j < 4; ++j) {
      int col = n0 + wn + j * 16 + lq;
      float bv = bias ? bf2f(bias[col]) : 0.f;
      #pragma unroll
      for (int i = 0; i < 4; ++i) {
        int rbase = m0 + wm + i * 16 + quad * 4;
        if (mode == 2) {
          int b = rbase >> 10, n = rbase & 1023;
          size_t idx = (((size_t)(b * CC + col)) << 10) + n;
          float4 xv = *reinterpret_cast<const float4*>(xres + idx);
          float4 o;
          o.x = acc[0 + i][j][0] * scale + bv + xv.x;
          o.y = acc[i][j][1] * scale + bv + xv.y;
          o.z = acc[i][j][2] * scale + bv + xv.z;
          o.w = acc[i][j][3] * scale + bv + xv.w;
          *reinterpret_cast<float4*>(outf + idx) = o;
        } else if (mode == 1) {
          int b = rbase >> 10, n = rbase & 1023;
          ushort4 o;
          o.x = f2bf(acc[i][j][0] * scale + bv);
          o.y = f2bf(acc[i][j][1] * scale + bv);
          o.z = f2bf(acc[i][j][2] * scale + bv);
          o.w = f2bf(acc[i][j][3] * scale + bv);
          *reinterpret_cast<ushort4*>(&Cb[(size_t)b * 262144 + (size_t)col * 1024 + n]) = o;
        } else {
          #pragma unroll
          for (int r = 0; r < 4; ++r)
            Cb[(size_t)(rbase + r) * ldc + col] = f2bf(acc[i][j][r] * scale + bv);
        }
      }
    }
  }
}

extern "C" void kernel_launch(void* const* d_in, const int* in_sizes, int n_in,
                              void* d_out, int out_size, void* d_ws, size_t ws_size,
                              hipStream_t stream) {
  const float* x     = (const float*)d_in[0];
  const float* gamma = (const float*)d_in[1];
  const float* beta  = (const float*)d_in[2];
  const float* Wkqv  = (const float*)d_in[3];
  const float* bkqv  = (const float*)d_in[4];
  const float* Wproj = (const float*)d_in[5];
  const float* bproj = (const float*)d_in[6];
  float* out = (float*)d_out;          // fp32 [32,256,32,32]

  // ---- workspace layout ----
  char* ws = (char*)d_ws;
  float* scl    = (float*)ws;                   // 256 f32
  float* sft    = (float*)(ws + 1024);          // 256 f32
  u16* Wkb = (u16*)(ws + 4096);                 // 196608 bf16
  u16* bkb = Wkb + 196608;
  u16* Wpb = bkb + 768;
  u16* bpb = Wpb + 65536;
  float* rowsum = (float*)(ws + 532480);        // 32*1024 f32 = 128 KB
  u16* qk   = (u16*)(ws + 1048576);             // [32768,512] bf16 = 32 MB
  u16* vt   = qk + (size_t)32768 * 512;         // [32,256,1024] bf16 = 16 MB
  u16* o_pv = vt + (size_t)32 * 256 * 1024;     // [32768,256] bf16 = 16 MB
  u16* Sc   = o_pv + (size_t)32768 * 256;       // S region (rest of ws)
  size_t s_base = 1048576 + (33554432 + 16777216 + 16777216);
  long avail = (long)ws_size - (long)s_base;
  int bpc = (int)(avail / 2097152);             // batches per S chunk (2 MB each)
  if (bpc < 1) bpc = 1;
  if (bpc > 32) bpc = 32;
  u16* t = (u16*)d_out;   // bf16 scratch in d_out, dead before mode-2 writes

  // 0. weight conversion + rowsum zero
  convert_w_kernel<<<dim3(1028), dim3(256), 0, stream>>>(
      Wkqv, bkqv, Wproj, bproj, Wkb, bkb, Wpb, bpb);
  hipMemsetAsync(rowsum, 0, 32 * 1024 * sizeof(float), stream);
  // 1. BN stats
  bn_stats_kernel<<<dim3(256), dim3(256), 0, stream>>>(x, gamma, beta, scl, sft);
  // 2. normalize + transpose -> t [B,N,C]
  norm_transpose_kernel<<<dim3(16, 4, 32), dim3(256), 0, stream>>>(x, scl, sft, t);
  // 3a. qk = t @ Wkqv[0:512]^T + b[0:512]
  gemm_nt_kernel<<<dim3(256, 4, 1), dim3(256), 0, stream>>>(
      t, 256, 0, Wkb, 256, 0, qk, 512, 0, 256, bkb, 1.0f, 0, nullptr, nullptr, nullptr);
  // 3b. vt[b,c,n] = (t @ Wkqv[512:768]^T + b[512:768])^T
  gemm_nt_kernel<<<dim3(256, 2, 1), dim3(256), 0, stream>>>(
      t, 256, 0, Wkb + 512 * 256, 256, 0, vt, 0, 0, 256, bkb + 512, 1.0f, 1,
      nullptr, nullptr, nullptr);
  // 4-7. attention: P=exp(QK^T/16) with fused row sums, then O = P V / l
  for (int b0 = 0; b0 < 32; b0 += bpc) {
    int nb = (32 - b0 < bpc) ? (32 - b0) : bpc;
    const u16* qc = qk + (size_t)b0 * 1024 * 512;
    gemm_nt_kernel<<<dim3(8, 8, nb), dim3(256), 0, stream>>>(
        qc, 512, (size_t)1024 * 512, qc + 256, 512, (size_t)1024 * 512,
        Sc, 1024, (size_t)1024 * 1024, 256, nullptr, 0.0625f, 3,
        nullptr, nullptr, rowsum + (size_t)b0 * 1024);
    gemm_nt_kernel<<<dim3(8, 2, nb), dim3(256), 0, stream>>>(
        Sc, 1024, (size_t)1024 * 1024, vt + (size_t)b0 * 262144, 1024, (size_t)262144,
        o_pv + (size_t)b0 * 262144, 256, (size_t)262144, 1024, nullptr, 1.0f, 4,
        nullptr, nullptr, rowsum + (size_t)b0 * 1024);
  }
  // 8+9 fused: out[b,c,n] = (o_pv @ Wproj^T + bproj)[n,c] + x[b,c,n]  (fp32)
  gemm_nt_kernel<<<dim3(256, 2, 1), dim3(256), 0, stream>>>(
      o_pv, 256, 0, Wpb, 256, 0, nullptr, 0, 0, 256, bpb, 1.0f, 2, x, out, nullptr);
}